// Round 1
// baseline (1665.387 us; speedup 1.0000x reference)
//
#include <hip/hip_runtime.h>
#include <cmath>
#include <cstddef>

// Dims (fixed by problem; N,E derived from in_sizes)
#define F_IN 128
#define H_DIM 64
#define C_OUT 40
#define MAXDEG 5

// ---------------- CSR build ----------------
__global__ void k_count(const int* __restrict__ src, const int* __restrict__ dst,
                        int E, int* __restrict__ cnt) {
    int e = blockIdx.x * blockDim.x + threadIdx.x;
    if (e >= E) return;
    int s = src[e], d = dst[e];
    if (s != d) atomicAdd(&cnt[d], 1);
}

__global__ void k_scanA(const int* __restrict__ cnt, int N,
                        int* __restrict__ row, int* __restrict__ bsum) {
    __shared__ int sh[1024];
    int tid = threadIdx.x;
    int gid = blockIdx.x * 1024 + tid;
    int v = (gid < N) ? cnt[gid] : 0;
    sh[tid] = v;
    __syncthreads();
    for (int off = 1; off < 1024; off <<= 1) {
        int t = (tid >= off) ? sh[tid - off] : 0;
        __syncthreads();
        sh[tid] += t;
        __syncthreads();
    }
    if (gid < N) row[gid] = sh[tid] - v;   // exclusive scan within block
    if (tid == 1023) bsum[blockIdx.x] = sh[tid];
}

__global__ void k_scanB(int* __restrict__ bsum, int G) {
    __shared__ int sh[1024];
    int tid = threadIdx.x;
    int v = (tid < G) ? bsum[tid] : 0;
    sh[tid] = v;
    __syncthreads();
    for (int off = 1; off < 1024; off <<= 1) {
        int t = (tid >= off) ? sh[tid - off] : 0;
        __syncthreads();
        sh[tid] += t;
        __syncthreads();
    }
    if (tid < G) bsum[tid] = sh[tid] - v;  // exclusive
}

__global__ void k_addoff(int* __restrict__ row, int* __restrict__ cursor,
                         const int* __restrict__ bsum, int N) {
    int i = blockIdx.x * blockDim.x + threadIdx.x;
    if (i >= N) return;
    int r = row[i] + bsum[i >> 10];
    row[i] = r;
    cursor[i] = r;
}

__global__ void k_fill(const int* __restrict__ src, const int* __restrict__ dst,
                       int E, int* __restrict__ cursor, int* __restrict__ col) {
    int e = blockIdx.x * blockDim.x + threadIdx.x;
    if (e >= E) return;
    int s = src[e], d = dst[e];
    if (s != d) {
        int slot = atomicAdd(&cursor[d], 1);
        col[slot] = s;
    }
}

// ---------------- h = relu(x @ W1 + b1), wave per node ----------------
__global__ void k_lin1(const float* __restrict__ x, const float* __restrict__ W1,
                       const float* __restrict__ b1, float* __restrict__ h, int N) {
    int gid = blockIdx.x * blockDim.x + threadIdx.x;
    int n = gid >> 6, lane = gid & 63;
    if (n >= N) return;
    const float* xr = x + (size_t)n * F_IN;
    float x0 = xr[lane];
    float x1 = xr[64 + lane];
    float acc = b1[lane];
#pragma unroll 16
    for (int k = 0; k < 64; ++k) {
        acc = fmaf(__shfl(x0, k), W1[k * H_DIM + lane], acc);
        acc = fmaf(__shfl(x1, k), W1[(k + 64) * H_DIM + lane], acc);
    }
    h[(size_t)n * H_DIM + lane] = fmaxf(acc, 0.0f);
}

// ---------------- agg[n] = h[n] + sum_{edges dst=n} h[src], wave per node ----------------
__global__ void k_agg(const float* __restrict__ hin, const int* __restrict__ row,
                      const int* __restrict__ cnt, const int* __restrict__ col,
                      float* __restrict__ agg, int N) {
    int gid = blockIdx.x * blockDim.x + threadIdx.x;
    int n = gid >> 6, lane = gid & 63;
    if (n >= N) return;
    int base = row[n];
    int c = cnt[n];
    float acc = hin[(size_t)n * H_DIM + lane];
    for (int j0 = 0; j0 < c; j0 += 64) {
        int myc = (j0 + lane < c) ? col[base + j0 + lane] : 0;
        int m = min(64, c - j0);
        for (int j = 0; j < m; ++j) {
            int s = __shfl(myc, j);
            acc += hin[(size_t)s * H_DIM + lane];
        }
    }
    agg[(size_t)n * H_DIM + lane] = acc;
}

// ---------------- h_out = agg @ relW[layer][deg] + relb[layer][deg] + fuse*x_first ----------------
__global__ void k_bucket(const float* __restrict__ agg, const int* __restrict__ cnt,
                         const float* __restrict__ relW, const float* __restrict__ relb,
                         const float* __restrict__ fuse, int layer,
                         const float* __restrict__ xfirst, float* __restrict__ hout, int N) {
    int gid = blockIdx.x * blockDim.x + threadIdx.x;
    int n = gid >> 6, lane = gid & 63;
    if (n >= N) return;
    int d = min(cnt[n], MAXDEG);
    const float* W = relW + ((size_t)(layer * 6 + d)) * (H_DIM * H_DIM);
    float a = agg[(size_t)n * H_DIM + lane];
    float acc = relb[(layer * 6 + d) * H_DIM + lane];
#pragma unroll 16
    for (int k = 0; k < 64; ++k) {
        acc = fmaf(__shfl(a, k), W[k * H_DIM + lane], acc);
    }
    float fu = fuse[layer];
    hout[(size_t)n * H_DIM + lane] = acc + fu * xfirst[(size_t)n * H_DIM + lane];
}

// ---------------- logits + log_softmax, wave per node ----------------
__global__ void k_out(const float* __restrict__ h, const float* __restrict__ Wout,
                      const float* __restrict__ bout, float* __restrict__ out, int N) {
    int gid = blockIdx.x * blockDim.x + threadIdx.x;
    int n = gid >> 6, lane = gid & 63;
    if (n >= N) return;
    float hv = h[(size_t)n * H_DIM + lane];
    float acc = (lane < C_OUT) ? bout[lane] : 0.0f;
#pragma unroll 16
    for (int k = 0; k < 64; ++k) {
        float w = (lane < C_OUT) ? Wout[k * C_OUT + lane] : 0.0f;
        acc = fmaf(__shfl(hv, k), w, acc);
    }
    float l = (lane < C_OUT) ? acc : -INFINITY;
    float m = l;
    for (int off = 32; off >= 1; off >>= 1) m = fmaxf(m, __shfl_xor(m, off));
    float e = (lane < C_OUT) ? expf(acc - m) : 0.0f;
    float s = e;
    for (int off = 32; off >= 1; off >>= 1) s += __shfl_xor(s, off);
    if (lane < C_OUT) out[(size_t)n * C_OUT + lane] = acc - m - logf(s);
}

extern "C" void kernel_launch(void* const* d_in, const int* in_sizes, int n_in,
                              void* d_out, int out_size, void* d_ws, size_t ws_size,
                              hipStream_t stream) {
    const float* x    = (const float*)d_in[0];
    const int*   ei   = (const int*)d_in[1];
    const float* W1   = (const float*)d_in[2];
    const float* b1   = (const float*)d_in[3];
    const float* relW = (const float*)d_in[4];
    const float* relb = (const float*)d_in[5];
    const float* Wout = (const float*)d_in[6];
    const float* bout = (const float*)d_in[7];
    const float* fuse = (const float*)d_in[8];
    float* out = (float*)d_out;

    int N = in_sizes[0] / F_IN;
    int E = in_sizes[1] / 2;
    const int* src = ei;
    const int* dst = ei + E;

    // workspace layout (256B aligned pieces)
    char* w = (char*)d_ws;
    auto alloc = [&](size_t bytes) {
        char* p = w;
        w += (bytes + 255) & ~(size_t)255;
        return p;
    };
    int*   cnt    = (int*)alloc((size_t)N * 4);
    int*   row    = (int*)alloc((size_t)N * 4);
    int*   cursor = (int*)alloc((size_t)N * 4);
    int*   bsum   = (int*)alloc(1024 * 4);
    int*   col    = (int*)alloc((size_t)E * 4);
    float* h0     = (float*)alloc((size_t)N * H_DIM * 4);
    float* h1     = (float*)alloc((size_t)N * H_DIM * 4);
    float* aggb   = (float*)alloc((size_t)N * H_DIM * 4);

    int G = (N + 1023) / 1024;  // 196 for N=200000

    hipMemsetAsync(cnt, 0, (size_t)N * 4, stream);
    k_count<<<(E + 255) / 256, 256, 0, stream>>>(src, dst, E, cnt);
    k_scanA<<<G, 1024, 0, stream>>>(cnt, N, row, bsum);
    k_scanB<<<1, 1024, 0, stream>>>(bsum, G);
    k_addoff<<<(N + 255) / 256, 256, 0, stream>>>(row, cursor, bsum, N);
    k_fill<<<(E + 255) / 256, 256, 0, stream>>>(src, dst, E, cursor, col);

    int nthr = N * H_DIM;
    int nblk = (nthr + 255) / 256;
    k_lin1<<<nblk, 256, 0, stream>>>(x, W1, b1, h0, N);

    // layer 0: h0 -> h1
    k_agg<<<nblk, 256, 0, stream>>>(h0, row, cnt, col, aggb, N);
    k_bucket<<<nblk, 256, 0, stream>>>(aggb, cnt, relW, relb, fuse, 0, h0, h1, N);
    // layer 1: h1 -> h1 (in-place safe: bucket reads agg/h0, writes h1)
    k_agg<<<nblk, 256, 0, stream>>>(h1, row, cnt, col, aggb, N);
    k_bucket<<<nblk, 256, 0, stream>>>(aggb, cnt, relW, relb, fuse, 1, h0, h1, N);

    k_out<<<nblk, 256, 0, stream>>>(h1, Wout, bout, out, N);
}

// Round 2
// 909.351 us; speedup vs baseline: 1.8314x; 1.8314x over previous
//
#include <hip/hip_runtime.h>
#include <cmath>
#include <cstddef>

#define F_IN 128
#define H_DIM 64
#define C_OUT 40
#define MAXDEG 5

typedef __attribute__((ext_vector_type(8))) short short8;
typedef __attribute__((ext_vector_type(4))) float fv4;

__device__ __forceinline__ float b2f(unsigned short u) {
    unsigned x = ((unsigned)u) << 16;
    return __builtin_bit_cast(float, x);
}
__device__ __forceinline__ unsigned short f2b(float f) {
    unsigned u = __builtin_bit_cast(unsigned, f);
    u = (u + 0x7FFF + ((u >> 16) & 1)) >> 16;
    return (unsigned short)u;
}

// ---------------- CSR build ----------------
__global__ void k_count(const int* __restrict__ src, const int* __restrict__ dst,
                        int E, int* __restrict__ cnt) {
    int e = blockIdx.x * blockDim.x + threadIdx.x;
    if (e >= E) return;
    int s = src[e], d = dst[e];
    if (s != d) atomicAdd(&cnt[d], 1);
}

__global__ void k_scanA(const int* __restrict__ cnt, int N,
                        int* __restrict__ row, int* __restrict__ bsum) {
    __shared__ int sh[1024];
    int tid = threadIdx.x;
    int gid = blockIdx.x * 1024 + tid;
    int v = (gid < N) ? cnt[gid] : 0;
    sh[tid] = v;
    __syncthreads();
    for (int off = 1; off < 1024; off <<= 1) {
        int t = (tid >= off) ? sh[tid - off] : 0;
        __syncthreads();
        sh[tid] += t;
        __syncthreads();
    }
    if (gid < N) row[gid] = sh[tid] - v;
    if (tid == 1023) bsum[blockIdx.x] = sh[tid];
}

__global__ void k_scanB(int* __restrict__ bsum, int G) {
    __shared__ int sh[1024];
    int tid = threadIdx.x;
    int v = (tid < G) ? bsum[tid] : 0;
    sh[tid] = v;
    __syncthreads();
    for (int off = 1; off < 1024; off <<= 1) {
        int t = (tid >= off) ? sh[tid - off] : 0;
        __syncthreads();
        sh[tid] += t;
        __syncthreads();
    }
    if (tid < G) bsum[tid] = sh[tid] - v;
}

__global__ void k_addoff(int* __restrict__ row, int* __restrict__ cursor,
                         const int* __restrict__ bsum, const int* __restrict__ cnt,
                         int* __restrict__ list, int* __restrict__ listctr, int N) {
    int i = blockIdx.x * blockDim.x + threadIdx.x;
    if (i >= N) return;
    int r = row[i] + bsum[i >> 10];
    row[i] = r;
    cursor[i] = r;
    if (cnt[i] < MAXDEG) {           // rare (deg ~ Poisson(16)): needs per-bucket fixup
        int p = atomicAdd(listctr, 1);
        list[p] = i;
    }
}

__global__ void k_fill(const int* __restrict__ src, const int* __restrict__ dst,
                       int E, int* __restrict__ cursor, int* __restrict__ col) {
    int e = blockIdx.x * blockDim.x + threadIdx.x;
    if (e >= E) return;
    int s = src[e], d = dst[e];
    if (s != d) {
        int slot = atomicAdd(&cursor[d], 1);
        col[slot] = s;
    }
}

// ---------------- h0 = relu(x @ W1 + b1), MFMA bf16, 16x16x32 ----------------
// W staged in LDS in B-fragment order: slot[(t*4+ks)*64 + lane]*8 + j
//   holds B[k = ks*32 + (lane>>4)*8 + j][n = t*16 + (lane&15)]
__global__ __launch_bounds__(256) void k_lin1(const float* __restrict__ x,
                                              const float* __restrict__ W1,
                                              const float* __restrict__ b1,
                                              unsigned short* __restrict__ h, int N) {
    __shared__ unsigned short Wl[4 * 4 * 64 * 8];  // 16 KB
    int tid = threadIdx.x;
    for (int idx = tid; idx < 4 * 4 * 64 * 8; idx += 256) {
        int j = idx & 7, ln = (idx >> 3) & 63, ks = (idx >> 9) & 3, t = idx >> 11;
        int k = ks * 32 + (ln >> 4) * 8 + j;
        int n = t * 16 + (ln & 15);
        Wl[idx] = f2b(W1[k * H_DIM + n]);
    }
    __syncthreads();

    int wave = tid >> 6, lane = tid & 63;
    int tile = blockIdx.x * 4 + wave;
    int row0 = tile * 16;
    if (row0 >= N) return;
    int m = lane & 15, quad = lane >> 4;
    int row = row0 + m;
    if (row >= N) row = N - 1;

    short8 a[4];
    const float* xr = x + (size_t)row * F_IN + quad * 8;
#pragma unroll
    for (int ks = 0; ks < 4; ++ks) {
        fv4 lo = *(const fv4*)(xr + ks * 32);
        fv4 hi = *(const fv4*)(xr + ks * 32 + 4);
        short8 av;
#pragma unroll
        for (int j = 0; j < 4; ++j) av[j] = (short)f2b(lo[j]);
#pragma unroll
        for (int j = 0; j < 4; ++j) av[4 + j] = (short)f2b(hi[j]);
        a[ks] = av;
    }

    fv4 acc[4];
#pragma unroll
    for (int t = 0; t < 4; ++t) acc[t] = (fv4){0.f, 0.f, 0.f, 0.f};
#pragma unroll
    for (int ks = 0; ks < 4; ++ks) {
#pragma unroll
        for (int t = 0; t < 4; ++t) {
            short8 b = *(const short8*)&Wl[(((t * 4 + ks) * 64) + lane) * 8];
            acc[t] = __builtin_amdgcn_mfma_f32_16x16x32_bf16(a[ks], b, acc[t], 0, 0, 0);
        }
    }
#pragma unroll
    for (int t = 0; t < 4; ++t) {
        int n = t * 16 + m;
        float bias = b1[n];
#pragma unroll
        for (int reg = 0; reg < 4; ++reg) {
            int r = row0 + quad * 4 + reg;
            if (r < N) {
                float v = acc[t][reg] + bias;
                h[(size_t)r * H_DIM + n] = f2b(fmaxf(v, 0.f));
            }
        }
    }
}

// ---------------- agg[n] = h[n] + sum h[src] (f32 accum, bf16 in/out) ----------------
__global__ void k_agg(const unsigned short* __restrict__ hin, const int* __restrict__ row,
                      const int* __restrict__ cnt, const int* __restrict__ col,
                      unsigned short* __restrict__ agg, int N) {
    int gid = blockIdx.x * blockDim.x + threadIdx.x;
    int n = gid >> 6, lane = gid & 63;
    if (n >= N) return;
    int base = row[n];
    int c = cnt[n];
    float acc = b2f(hin[(size_t)n * H_DIM + lane]);
    for (int j0 = 0; j0 < c; j0 += 64) {
        int idx = j0 + lane;
        int myc = (idx < c) ? col[base + idx] : 0;
        int mm = min(64, c - j0);
        int j = 0;
        for (; j + 8 <= mm; j += 8) {
            int s0 = __shfl(myc, j + 0), s1 = __shfl(myc, j + 1);
            int s2 = __shfl(myc, j + 2), s3 = __shfl(myc, j + 3);
            int s4 = __shfl(myc, j + 4), s5 = __shfl(myc, j + 5);
            int s6 = __shfl(myc, j + 6), s7 = __shfl(myc, j + 7);
            float v0 = b2f(hin[(size_t)s0 * H_DIM + lane]);
            float v1 = b2f(hin[(size_t)s1 * H_DIM + lane]);
            float v2 = b2f(hin[(size_t)s2 * H_DIM + lane]);
            float v3 = b2f(hin[(size_t)s3 * H_DIM + lane]);
            float v4 = b2f(hin[(size_t)s4 * H_DIM + lane]);
            float v5 = b2f(hin[(size_t)s5 * H_DIM + lane]);
            float v6 = b2f(hin[(size_t)s6 * H_DIM + lane]);
            float v7 = b2f(hin[(size_t)s7 * H_DIM + lane]);
            acc += ((v0 + v1) + (v2 + v3)) + ((v4 + v5) + (v6 + v7));
        }
        for (; j < mm; ++j) {
            int s = __shfl(myc, j);
            acc += b2f(hin[(size_t)s * H_DIM + lane]);
        }
    }
    agg[(size_t)n * H_DIM + lane] = f2b(acc);
}

// ---------------- bucket-5 GEMM for ALL nodes: h = agg@W5 + b5 + fuse*xfirst ----------------
__global__ __launch_bounds__(256) void k_bucket(const unsigned short* __restrict__ agg,
                                                const float* __restrict__ relW,
                                                const float* __restrict__ relb,
                                                const float* __restrict__ fuse, int layer,
                                                const unsigned short* __restrict__ xfirst,
                                                unsigned short* __restrict__ h, int N) {
    __shared__ unsigned short Wl[4 * 2 * 64 * 8];  // 8 KB
    const float* W = relW + (size_t)(layer * 6 + MAXDEG) * (H_DIM * H_DIM);
    int tid = threadIdx.x;
    for (int idx = tid; idx < 4 * 2 * 64 * 8; idx += 256) {
        int j = idx & 7, ln = (idx >> 3) & 63, ks = (idx >> 9) & 1, t = idx >> 10;
        int k = ks * 32 + (ln >> 4) * 8 + j;
        int n = t * 16 + (ln & 15);
        Wl[idx] = f2b(W[k * H_DIM + n]);
    }
    __syncthreads();

    int wave = tid >> 6, lane = tid & 63;
    int tile = blockIdx.x * 4 + wave;
    int row0 = tile * 16;
    if (row0 >= N) return;
    int m = lane & 15, quad = lane >> 4;
    int row = row0 + m;
    if (row >= N) row = N - 1;

    short8 a[2];
#pragma unroll
    for (int ks = 0; ks < 2; ++ks)
        a[ks] = *(const short8*)(agg + (size_t)row * H_DIM + ks * 32 + quad * 8);

    fv4 acc[4];
#pragma unroll
    for (int t = 0; t < 4; ++t) acc[t] = (fv4){0.f, 0.f, 0.f, 0.f};
#pragma unroll
    for (int ks = 0; ks < 2; ++ks) {
#pragma unroll
        for (int t = 0; t < 4; ++t) {
            short8 b = *(const short8*)&Wl[(((t * 2 + ks) * 64) + lane) * 8];
            acc[t] = __builtin_amdgcn_mfma_f32_16x16x32_bf16(a[ks], b, acc[t], 0, 0, 0);
        }
    }
    float fu = fuse[layer];
    const float* bias = relb + (layer * 6 + MAXDEG) * H_DIM;
#pragma unroll
    for (int t = 0; t < 4; ++t) {
        int n = t * 16 + m;
        float bv = bias[n];
#pragma unroll
        for (int reg = 0; reg < 4; ++reg) {
            int r = row0 + quad * 4 + reg;
            if (r < N) {
                float v = acc[t][reg] + bv + fu * b2f(xfirst[(size_t)r * H_DIM + n]);
                h[(size_t)r * H_DIM + n] = f2b(v);
            }
        }
    }
}

// ---------------- fixup for rare deg<5 nodes: recompute with their bucket ----------------
__global__ void k_fixup(const unsigned short* __restrict__ agg, const int* __restrict__ list,
                        const int* __restrict__ listctr, const int* __restrict__ cnt,
                        const float* __restrict__ relW, const float* __restrict__ relb,
                        const float* __restrict__ fuse, int layer,
                        const unsigned short* __restrict__ xfirst,
                        unsigned short* __restrict__ h) {
    int gid = blockIdx.x * blockDim.x + threadIdx.x;
    int wave = gid >> 6, lane = gid & 63;
    int nwaves = (gridDim.x * blockDim.x) >> 6;
    int M = *listctr;
    float fu = fuse[layer];
    for (int i = wave; i < M; i += nwaves) {
        int n = list[i];
        int d = cnt[n];  // < 5
        const float* W = relW + (size_t)(layer * 6 + d) * (H_DIM * H_DIM);
        float a = b2f(agg[(size_t)n * H_DIM + lane]);
        float acc = relb[(layer * 6 + d) * H_DIM + lane];
#pragma unroll 16
        for (int k = 0; k < 64; ++k)
            acc = fmaf(__shfl(a, k), W[k * H_DIM + lane], acc);
        acc += fu * b2f(xfirst[(size_t)n * H_DIM + lane]);
        h[(size_t)n * H_DIM + lane] = f2b(acc);
    }
}

// ---------------- logits + log_softmax via MFMA ----------------
__global__ __launch_bounds__(256) void k_out(const unsigned short* __restrict__ h,
                                             const float* __restrict__ Wout,
                                             const float* __restrict__ bout,
                                             float* __restrict__ out, int N) {
    __shared__ unsigned short Wl[3 * 2 * 64 * 8];  // 6 KB, cols >= 40 zeroed
    int tid = threadIdx.x;
    for (int idx = tid; idx < 3 * 2 * 64 * 8; idx += 256) {
        int j = idx & 7, ln = (idx >> 3) & 63, ks = (idx >> 9) & 1, t = idx >> 10;
        int k = ks * 32 + (ln >> 4) * 8 + j;
        int n = t * 16 + (ln & 15);
        Wl[idx] = (n < C_OUT) ? f2b(Wout[k * C_OUT + n]) : 0;
    }
    __syncthreads();

    int wave = tid >> 6, lane = tid & 63;
    int tile = blockIdx.x * 4 + wave;
    int row0 = tile * 16;
    if (row0 >= N) return;
    int m = lane & 15, quad = lane >> 4;
    int row = row0 + m;
    if (row >= N) row = N - 1;

    short8 a[2];
#pragma unroll
    for (int ks = 0; ks < 2; ++ks)
        a[ks] = *(const short8*)(h + (size_t)row * H_DIM + ks * 32 + quad * 8);

    fv4 acc[3];
#pragma unroll
    for (int t = 0; t < 3; ++t) acc[t] = (fv4){0.f, 0.f, 0.f, 0.f};
#pragma unroll
    for (int ks = 0; ks < 2; ++ks) {
#pragma unroll
        for (int t = 0; t < 3; ++t) {
            short8 b = *(const short8*)&Wl[(((t * 2 + ks) * 64) + lane) * 8];
            acc[t] = __builtin_amdgcn_mfma_f32_16x16x32_bf16(a[ks], b, acc[t], 0, 0, 0);
        }
    }
    bool v2 = (m < 8);  // col 32 + m < 40
    float b0 = bout[m], b1v = bout[16 + m], b2v = v2 ? bout[32 + m] : 0.f;
#pragma unroll
    for (int reg = 0; reg < 4; ++reg) {
        int r = row0 + quad * 4 + reg;
        float l0 = acc[0][reg] + b0;
        float l1 = acc[1][reg] + b1v;
        float l2 = v2 ? (acc[2][reg] + b2v) : -INFINITY;
        float mx = fmaxf(fmaxf(l0, l1), l2);
#pragma unroll
        for (int off = 1; off < 16; off <<= 1) mx = fmaxf(mx, __shfl_xor(mx, off));
        float s = expf(l0 - mx) + expf(l1 - mx) + (v2 ? expf(l2 - mx) : 0.f);
#pragma unroll
        for (int off = 1; off < 16; off <<= 1) s += __shfl_xor(s, off);
        float ls = logf(s);
        if (r < N) {
            out[(size_t)r * C_OUT + m] = l0 - mx - ls;
            out[(size_t)r * C_OUT + 16 + m] = l1 - mx - ls;
            if (v2) out[(size_t)r * C_OUT + 32 + m] = l2 - mx - ls;
        }
    }
}

extern "C" void kernel_launch(void* const* d_in, const int* in_sizes, int n_in,
                              void* d_out, int out_size, void* d_ws, size_t ws_size,
                              hipStream_t stream) {
    const float* x    = (const float*)d_in[0];
    const int*   ei   = (const int*)d_in[1];
    const float* W1   = (const float*)d_in[2];
    const float* b1   = (const float*)d_in[3];
    const float* relW = (const float*)d_in[4];
    const float* relb = (const float*)d_in[5];
    const float* Wout = (const float*)d_in[6];
    const float* bout = (const float*)d_in[7];
    const float* fuse = (const float*)d_in[8];
    float* out = (float*)d_out;

    int N = in_sizes[0] / F_IN;
    int E = in_sizes[1] / 2;
    const int* src = ei;
    const int* dst = ei + E;

    char* w = (char*)d_ws;
    auto alloc = [&](size_t bytes) {
        char* p = w;
        w += (bytes + 255) & ~(size_t)255;
        return p;
    };
    int* cnt     = (int*)alloc((size_t)N * 4);
    int* row     = (int*)alloc((size_t)N * 4);
    int* cursor  = (int*)alloc((size_t)N * 4);
    int* bsum    = (int*)alloc(1024 * 4);
    int* list    = (int*)alloc((size_t)N * 4);
    int* listctr = (int*)alloc(256);
    int* col     = (int*)alloc((size_t)E * 4);
    unsigned short* h0   = (unsigned short*)alloc((size_t)N * H_DIM * 2);
    unsigned short* h1   = (unsigned short*)alloc((size_t)N * H_DIM * 2);
    unsigned short* aggb = (unsigned short*)alloc((size_t)N * H_DIM * 2);

    int G = (N + 1023) / 1024;

    hipMemsetAsync(cnt, 0, (size_t)N * 4, stream);
    hipMemsetAsync(listctr, 0, 4, stream);
    k_count<<<(E + 255) / 256, 256, 0, stream>>>(src, dst, E, cnt);
    k_scanA<<<G, 1024, 0, stream>>>(cnt, N, row, bsum);
    k_scanB<<<1, 1024, 0, stream>>>(bsum, G);
    k_addoff<<<(N + 255) / 256, 256, 0, stream>>>(row, cursor, bsum, cnt, list, listctr, N);
    k_fill<<<(E + 255) / 256, 256, 0, stream>>>(src, dst, E, cursor, col);

    int tiles = (N + 15) / 16;
    int gblk = (tiles + 3) / 4;     // 4 waves (tiles) per block
    int ablk = ((size_t)N * 64 + 255) / 256;

    k_lin1<<<gblk, 256, 0, stream>>>(x, W1, b1, h0, N);

    // layer 0
    k_agg<<<ablk, 256, 0, stream>>>(h0, row, cnt, col, aggb, N);
    k_bucket<<<gblk, 256, 0, stream>>>(aggb, relW, relb, fuse, 0, h0, h1, N);
    k_fixup<<<16, 256, 0, stream>>>(aggb, list, listctr, cnt, relW, relb, fuse, 0, h0, h1);
    // layer 1
    k_agg<<<ablk, 256, 0, stream>>>(h1, row, cnt, col, aggb, N);
    k_bucket<<<gblk, 256, 0, stream>>>(aggb, relW, relb, fuse, 1, h0, h1, N);
    k_fixup<<<16, 256, 0, stream>>>(aggb, list, listctr, cnt, relW, relb, fuse, 1, h0, h1);

    k_out<<<gblk, 256, 0, stream>>>(h1, Wout, bout, out, N);
}

// Round 3
// 604.874 us; speedup vs baseline: 2.7533x; 1.5034x over previous
//
#include <hip/hip_runtime.h>
#include <cmath>
#include <cstddef>

#define F_IN 128
#define H_DIM 64
#define C_OUT 40
#define MAXDEG 5
#define EPB 16

typedef __attribute__((ext_vector_type(8))) short short8;
typedef __attribute__((ext_vector_type(4))) float fv4;

__device__ __forceinline__ float b2f(unsigned short u) {
    unsigned x = ((unsigned)u) << 16;
    return __builtin_bit_cast(float, x);
}
__device__ __forceinline__ unsigned short f2b(float f) {
    unsigned u = __builtin_bit_cast(unsigned, f);
    u = (u + 0x7FFF + ((u >> 16) & 1)) >> 16;
    return (unsigned short)u;
}

// ============ CSR build via 1024-node bucket sort ============
// bucket b = dst >> 10; packed edge = (dst&1023)<<20 | src  (needs src < 2^20)

__global__ void k_hist(const int* __restrict__ src, const int* __restrict__ dst,
                       int E, int NB, int* __restrict__ bkt_cnt) {
    __shared__ int h[1024];
    for (int i = threadIdx.x; i < NB; i += blockDim.x) h[i] = 0;
    __syncthreads();
    int stride = gridDim.x * blockDim.x;
    for (int e = blockIdx.x * blockDim.x + threadIdx.x; e < E; e += stride) {
        int s = src[e], d = dst[e];
        if (s != d) atomicAdd(&h[d >> 10], 1);
    }
    __syncthreads();
    for (int i = threadIdx.x; i < NB; i += blockDim.x)
        if (h[i]) atomicAdd(&bkt_cnt[i], h[i]);
}

__global__ void k_bktscan(const int* __restrict__ bkt_cnt, int NB,
                          int* __restrict__ bkt_off, int* __restrict__ gcur) {
    __shared__ int sh[1024];
    int tid = threadIdx.x;
    int v = (tid < NB) ? bkt_cnt[tid] : 0;
    sh[tid] = v;
    __syncthreads();
    for (int off = 1; off < 1024; off <<= 1) {
        int t = (tid >= off) ? sh[tid - off] : 0;
        __syncthreads();
        sh[tid] += t;
        __syncthreads();
    }
    if (tid < NB) {
        int ex = sh[tid] - v;
        bkt_off[tid] = ex;
        gcur[tid] = ex;
    }
    if (tid == 1023) bkt_off[NB] = sh[1023];
}

__global__ __launch_bounds__(256) void k_scatter(const int* __restrict__ src,
                                                 const int* __restrict__ dst,
                                                 int E, int NB, int* __restrict__ gcur,
                                                 unsigned int* __restrict__ ebuf) {
    __shared__ int hist[1024];
    __shared__ int base[1024];
    for (int i = threadIdx.x; i < NB; i += 256) hist[i] = 0;
    __syncthreads();
    int e0 = blockIdx.x * (256 * EPB);
    int es[EPB], ed[EPB];
#pragma unroll
    for (int i = 0; i < EPB; ++i) {
        int e = e0 + i * 256 + threadIdx.x;
        int s = -1, d = -1;
        if (e < E) { s = src[e]; d = dst[e]; }
        es[i] = s; ed[i] = d;
        if (d >= 0 && s != d) atomicAdd(&hist[d >> 10], 1);
    }
    __syncthreads();
    for (int i = threadIdx.x; i < NB; i += 256) {
        int c = hist[i];
        base[i] = c ? atomicAdd(&gcur[i], c) : 0;
    }
    __syncthreads();
    for (int i = threadIdx.x; i < NB; i += 256) hist[i] = 0;
    __syncthreads();
#pragma unroll
    for (int i = 0; i < EPB; ++i) {
        int s = es[i], d = ed[i];
        if (d >= 0 && s != d) {
            int b = d >> 10;
            int p = atomicAdd(&hist[b], 1);
            ebuf[base[b] + p] = ((unsigned)(d & 1023) << 20) | (unsigned)s;
        }
    }
}

__global__ __launch_bounds__(1024) void k_build(const unsigned int* __restrict__ ebuf,
                                                const int* __restrict__ bkt_off, int N,
                                                int* __restrict__ row, int* __restrict__ cnt,
                                                int* __restrict__ col, int* __restrict__ list,
                                                int* __restrict__ listctr) {
    __shared__ int lcnt[1024];
    __shared__ int lcur[1024];
    int bk = blockIdx.x;
    int n0 = bk << 10;
    int tid = threadIdx.x;
    int ebase = bkt_off[bk], eend = bkt_off[bk + 1];
    lcnt[tid] = 0;
    __syncthreads();
    for (int e = ebase + tid; e < eend; e += 1024)
        atomicAdd(&lcnt[ebuf[e] >> 20], 1);
    __syncthreads();
    int v = lcnt[tid];
    lcur[tid] = v;
    __syncthreads();
    for (int off = 1; off < 1024; off <<= 1) {
        int t = (tid >= off) ? lcur[tid - off] : 0;
        __syncthreads();
        lcur[tid] += t;
        __syncthreads();
    }
    int ex = lcur[tid] - v;
    __syncthreads();
    lcur[tid] = ebase + ex;
    int n = n0 + tid;
    if (n < N) {
        row[n] = ebase + ex;
        cnt[n] = v;
        if (v < MAXDEG) {
            int p = atomicAdd(listctr, 1);
            list[p] = n;
        }
    }
    __syncthreads();
    for (int e = ebase + tid; e < eend; e += 1024) {
        unsigned edv = ebuf[e];
        int dl = edv >> 20;
        int p = atomicAdd(&lcur[dl], 1);
        col[p] = (int)(edv & 0xFFFFF);
    }
}

// ---------------- h0 = relu(x @ W1 + b1), MFMA bf16 ----------------
__global__ __launch_bounds__(256) void k_lin1(const float* __restrict__ x,
                                              const float* __restrict__ W1,
                                              const float* __restrict__ b1,
                                              unsigned short* __restrict__ h, int N) {
    __shared__ unsigned short Wl[4 * 4 * 64 * 8];
    int tid = threadIdx.x;
    for (int idx = tid; idx < 4 * 4 * 64 * 8; idx += 256) {
        int j = idx & 7, ln = (idx >> 3) & 63, ks = (idx >> 9) & 3, t = idx >> 11;
        int k = ks * 32 + (ln >> 4) * 8 + j;
        int n = t * 16 + (ln & 15);
        Wl[idx] = f2b(W1[k * H_DIM + n]);
    }
    __syncthreads();

    int wave = tid >> 6, lane = tid & 63;
    int tile = blockIdx.x * 4 + wave;
    int row0 = tile * 16;
    if (row0 >= N) return;
    int m = lane & 15, quad = lane >> 4;
    int row = row0 + m;
    if (row >= N) row = N - 1;

    short8 a[4];
    const float* xr = x + (size_t)row * F_IN + quad * 8;
#pragma unroll
    for (int ks = 0; ks < 4; ++ks) {
        fv4 lo = *(const fv4*)(xr + ks * 32);
        fv4 hi = *(const fv4*)(xr + ks * 32 + 4);
        short8 av;
#pragma unroll
        for (int j = 0; j < 4; ++j) av[j] = (short)f2b(lo[j]);
#pragma unroll
        for (int j = 0; j < 4; ++j) av[4 + j] = (short)f2b(hi[j]);
        a[ks] = av;
    }

    fv4 acc[4];
#pragma unroll
    for (int t = 0; t < 4; ++t) acc[t] = (fv4){0.f, 0.f, 0.f, 0.f};
#pragma unroll
    for (int ks = 0; ks < 4; ++ks) {
#pragma unroll
        for (int t = 0; t < 4; ++t) {
            short8 b = *(const short8*)&Wl[(((t * 4 + ks) * 64) + lane) * 8];
            acc[t] = __builtin_amdgcn_mfma_f32_16x16x32_bf16(a[ks], b, acc[t], 0, 0, 0);
        }
    }
#pragma unroll
    for (int t = 0; t < 4; ++t) {
        int n = t * 16 + m;
        float bias = b1[n];
#pragma unroll
        for (int reg = 0; reg < 4; ++reg) {
            int r = row0 + quad * 4 + reg;
            if (r < N) {
                float v = acc[t][reg] + bias;
                h[(size_t)r * H_DIM + n] = f2b(fmaxf(v, 0.f));
            }
        }
    }
}

// ---------------- agg[n] = h[n] + sum h[src] ----------------
__global__ void k_agg(const unsigned short* __restrict__ hin, const int* __restrict__ row,
                      const int* __restrict__ cnt, const int* __restrict__ col,
                      unsigned short* __restrict__ agg, int N) {
    int gid = blockIdx.x * blockDim.x + threadIdx.x;
    int n = gid >> 6, lane = gid & 63;
    if (n >= N) return;
    int base = row[n];
    int c = cnt[n];
    float acc = b2f(hin[(size_t)n * H_DIM + lane]);
    for (int j0 = 0; j0 < c; j0 += 64) {
        int idx = j0 + lane;
        int myc = (idx < c) ? col[base + idx] : 0;
        int mm = min(64, c - j0);
        int j = 0;
        for (; j + 8 <= mm; j += 8) {
            int s0 = __shfl(myc, j + 0), s1 = __shfl(myc, j + 1);
            int s2 = __shfl(myc, j + 2), s3 = __shfl(myc, j + 3);
            int s4 = __shfl(myc, j + 4), s5 = __shfl(myc, j + 5);
            int s6 = __shfl(myc, j + 6), s7 = __shfl(myc, j + 7);
            float v0 = b2f(hin[(size_t)s0 * H_DIM + lane]);
            float v1 = b2f(hin[(size_t)s1 * H_DIM + lane]);
            float v2 = b2f(hin[(size_t)s2 * H_DIM + lane]);
            float v3 = b2f(hin[(size_t)s3 * H_DIM + lane]);
            float v4 = b2f(hin[(size_t)s4 * H_DIM + lane]);
            float v5 = b2f(hin[(size_t)s5 * H_DIM + lane]);
            float v6 = b2f(hin[(size_t)s6 * H_DIM + lane]);
            float v7 = b2f(hin[(size_t)s7 * H_DIM + lane]);
            acc += ((v0 + v1) + (v2 + v3)) + ((v4 + v5) + (v6 + v7));
        }
        for (; j < mm; ++j) {
            int s = __shfl(myc, j);
            acc += b2f(hin[(size_t)s * H_DIM + lane]);
        }
    }
    agg[(size_t)n * H_DIM + lane] = f2b(acc);
}

// ---------------- bucket-5 GEMM for ALL nodes ----------------
__global__ __launch_bounds__(256) void k_bucket(const unsigned short* __restrict__ agg,
                                                const float* __restrict__ relW,
                                                const float* __restrict__ relb,
                                                const float* __restrict__ fuse, int layer,
                                                const unsigned short* __restrict__ xfirst,
                                                unsigned short* __restrict__ h, int N) {
    __shared__ unsigned short Wl[4 * 2 * 64 * 8];
    const float* W = relW + (size_t)(layer * 6 + MAXDEG) * (H_DIM * H_DIM);
    int tid = threadIdx.x;
    for (int idx = tid; idx < 4 * 2 * 64 * 8; idx += 256) {
        int j = idx & 7, ln = (idx >> 3) & 63, ks = (idx >> 9) & 1, t = idx >> 10;
        int k = ks * 32 + (ln >> 4) * 8 + j;
        int n = t * 16 + (ln & 15);
        Wl[idx] = f2b(W[k * H_DIM + n]);
    }
    __syncthreads();

    int wave = tid >> 6, lane = tid & 63;
    int tile = blockIdx.x * 4 + wave;
    int row0 = tile * 16;
    if (row0 >= N) return;
    int m = lane & 15, quad = lane >> 4;
    int row = row0 + m;
    if (row >= N) row = N - 1;

    short8 a[2];
#pragma unroll
    for (int ks = 0; ks < 2; ++ks)
        a[ks] = *(const short8*)(agg + (size_t)row * H_DIM + ks * 32 + quad * 8);

    fv4 acc[4];
#pragma unroll
    for (int t = 0; t < 4; ++t) acc[t] = (fv4){0.f, 0.f, 0.f, 0.f};
#pragma unroll
    for (int ks = 0; ks < 2; ++ks) {
#pragma unroll
        for (int t = 0; t < 4; ++t) {
            short8 b = *(const short8*)&Wl[(((t * 2 + ks) * 64) + lane) * 8];
            acc[t] = __builtin_amdgcn_mfma_f32_16x16x32_bf16(a[ks], b, acc[t], 0, 0, 0);
        }
    }
    float fu = fuse[layer];
    const float* bias = relb + (layer * 6 + MAXDEG) * H_DIM;
#pragma unroll
    for (int t = 0; t < 4; ++t) {
        int n = t * 16 + m;
        float bv = bias[n];
#pragma unroll
        for (int reg = 0; reg < 4; ++reg) {
            int r = row0 + quad * 4 + reg;
            if (r < N) {
                float v = acc[t][reg] + bv + fu * b2f(xfirst[(size_t)r * H_DIM + n]);
                h[(size_t)r * H_DIM + n] = f2b(v);
            }
        }
    }
}

// ---------------- fixup for rare deg<5 nodes ----------------
__global__ void k_fixup(const unsigned short* __restrict__ agg, const int* __restrict__ list,
                        const int* __restrict__ listctr, const int* __restrict__ cnt,
                        const float* __restrict__ relW, const float* __restrict__ relb,
                        const float* __restrict__ fuse, int layer,
                        const unsigned short* __restrict__ xfirst,
                        unsigned short* __restrict__ h) {
    int gid = blockIdx.x * blockDim.x + threadIdx.x;
    int wave = gid >> 6, lane = gid & 63;
    int nwaves = (gridDim.x * blockDim.x) >> 6;
    int M = *listctr;
    float fu = fuse[layer];
    for (int i = wave; i < M; i += nwaves) {
        int n = list[i];
        int d = cnt[n];
        const float* W = relW + (size_t)(layer * 6 + d) * (H_DIM * H_DIM);
        float a = b2f(agg[(size_t)n * H_DIM + lane]);
        float acc = relb[(layer * 6 + d) * H_DIM + lane];
#pragma unroll 16
        for (int k = 0; k < 64; ++k)
            acc = fmaf(__shfl(a, k), W[k * H_DIM + lane], acc);
        acc += fu * b2f(xfirst[(size_t)n * H_DIM + lane]);
        h[(size_t)n * H_DIM + lane] = f2b(acc);
    }
}

// ---------------- logits + log_softmax via MFMA ----------------
__global__ __launch_bounds__(256) void k_out(const unsigned short* __restrict__ h,
                                             const float* __restrict__ Wout,
                                             const float* __restrict__ bout,
                                             float* __restrict__ out, int N) {
    __shared__ unsigned short Wl[3 * 2 * 64 * 8];
    int tid = threadIdx.x;
    for (int idx = tid; idx < 3 * 2 * 64 * 8; idx += 256) {
        int j = idx & 7, ln = (idx >> 3) & 63, ks = (idx >> 9) & 1, t = idx >> 10;
        int k = ks * 32 + (ln >> 4) * 8 + j;
        int n = t * 16 + (ln & 15);
        Wl[idx] = (n < C_OUT) ? f2b(Wout[k * C_OUT + n]) : 0;
    }
    __syncthreads();

    int wave = tid >> 6, lane = tid & 63;
    int tile = blockIdx.x * 4 + wave;
    int row0 = tile * 16;
    if (row0 >= N) return;
    int m = lane & 15, quad = lane >> 4;
    int row = row0 + m;
    if (row >= N) row = N - 1;

    short8 a[2];
#pragma unroll
    for (int ks = 0; ks < 2; ++ks)
        a[ks] = *(const short8*)(h + (size_t)row * H_DIM + ks * 32 + quad * 8);

    fv4 acc[3];
#pragma unroll
    for (int t = 0; t < 3; ++t) acc[t] = (fv4){0.f, 0.f, 0.f, 0.f};
#pragma unroll
    for (int ks = 0; ks < 2; ++ks) {
#pragma unroll
        for (int t = 0; t < 3; ++t) {
            short8 b = *(const short8*)&Wl[(((t * 2 + ks) * 64) + lane) * 8];
            acc[t] = __builtin_amdgcn_mfma_f32_16x16x32_bf16(a[ks], b, acc[t], 0, 0, 0);
        }
    }
    bool v2 = (m < 8);
    float b0 = bout[m], b1v = bout[16 + m], b2v = v2 ? bout[32 + m] : 0.f;
#pragma unroll
    for (int reg = 0; reg < 4; ++reg) {
        int r = row0 + quad * 4 + reg;
        float l0 = acc[0][reg] + b0;
        float l1 = acc[1][reg] + b1v;
        float l2 = v2 ? (acc[2][reg] + b2v) : -INFINITY;
        float mx = fmaxf(fmaxf(l0, l1), l2);
#pragma unroll
        for (int off = 1; off < 16; off <<= 1) mx = fmaxf(mx, __shfl_xor(mx, off));
        float s = expf(l0 - mx) + expf(l1 - mx) + (v2 ? expf(l2 - mx) : 0.f);
#pragma unroll
        for (int off = 1; off < 16; off <<= 1) s += __shfl_xor(s, off);
        float ls = logf(s);
        if (r < N) {
            out[(size_t)r * C_OUT + m] = l0 - mx - ls;
            out[(size_t)r * C_OUT + 16 + m] = l1 - mx - ls;
            if (v2) out[(size_t)r * C_OUT + 32 + m] = l2 - mx - ls;
        }
    }
}

extern "C" void kernel_launch(void* const* d_in, const int* in_sizes, int n_in,
                              void* d_out, int out_size, void* d_ws, size_t ws_size,
                              hipStream_t stream) {
    const float* x    = (const float*)d_in[0];
    const int*   ei   = (const int*)d_in[1];
    const float* W1   = (const float*)d_in[2];
    const float* b1   = (const float*)d_in[3];
    const float* relW = (const float*)d_in[4];
    const float* relb = (const float*)d_in[5];
    const float* Wout = (const float*)d_in[6];
    const float* bout = (const float*)d_in[7];
    const float* fuse = (const float*)d_in[8];
    float* out = (float*)d_out;

    int N = in_sizes[0] / F_IN;
    int E = in_sizes[1] / 2;
    const int* src = ei;
    const int* dst = ei + E;
    int NB = (N + 1023) >> 10;   // 1024-node buckets; requires N < 2^20 for packing

    char* w = (char*)d_ws;
    auto alloc = [&](size_t bytes) {
        char* p = w;
        w += (bytes + 255) & ~(size_t)255;
        return p;
    };
    int* cnt     = (int*)alloc((size_t)N * 4);
    int* row     = (int*)alloc((size_t)N * 4);
    int* list    = (int*)alloc((size_t)N * 4);
    int* listctr = (int*)alloc(256);
    int* bkt_cnt = (int*)alloc(1056 * 4);
    int* bkt_off = (int*)alloc(1056 * 4);
    int* gcur    = (int*)alloc(1056 * 4);
    int* col     = (int*)alloc((size_t)E * 4);
    unsigned short* h0   = (unsigned short*)alloc((size_t)N * H_DIM * 2);
    unsigned short* h1   = (unsigned short*)alloc((size_t)N * H_DIM * 2);
    unsigned short* aggb = (unsigned short*)alloc((size_t)N * H_DIM * 2);
    unsigned int* ebuf = (unsigned int*)aggb;  // alias: ebuf dead before k_agg writes aggb

    hipMemsetAsync(bkt_cnt, 0, 1056 * 4, stream);
    hipMemsetAsync(listctr, 0, 4, stream);

    k_hist<<<512, 256, 0, stream>>>(src, dst, E, NB, bkt_cnt);
    k_bktscan<<<1, 1024, 0, stream>>>(bkt_cnt, NB, bkt_off, gcur);
    k_scatter<<<(E + 256 * EPB - 1) / (256 * EPB), 256, 0, stream>>>(src, dst, E, NB, gcur, ebuf);
    k_build<<<NB, 1024, 0, stream>>>(ebuf, bkt_off, N, row, cnt, col, list, listctr);

    int tiles = (N + 15) / 16;
    int gblk = (tiles + 3) / 4;
    int ablk = ((size_t)N * 64 + 255) / 256;

    k_lin1<<<gblk, 256, 0, stream>>>(x, W1, b1, h0, N);

    k_agg<<<ablk, 256, 0, stream>>>(h0, row, cnt, col, aggb, N);
    k_bucket<<<gblk, 256, 0, stream>>>(aggb, relW, relb, fuse, 0, h0, h1, N);
    k_fixup<<<16, 256, 0, stream>>>(aggb, list, listctr, cnt, relW, relb, fuse, 0, h0, h1);

    k_agg<<<ablk, 256, 0, stream>>>(h1, row, cnt, col, aggb, N);
    k_bucket<<<gblk, 256, 0, stream>>>(aggb, relW, relb, fuse, 1, h0, h1, N);
    k_fixup<<<16, 256, 0, stream>>>(aggb, list, listctr, cnt, relW, relb, fuse, 1, h0, h1);

    k_out<<<gblk, 256, 0, stream>>>(h1, Wout, bout, out, N);
}